// Round 11
// baseline (63.629 us; speedup 1.0000x reference)
//
#include <hip/hip_runtime.h>
#include <math.h>

#define NFFT   1024
#define FREQ   513
#define FRAMES 256
#define SIGLEN 66560          // 256*256 + 1024
#define NB     4
#define BFT    (NB * FREQ * FRAMES)   // 525312
#define NWAVE  4               // waves per block (n-loop split factor)
#define NTHR   (64 * NWAVE)    // 256
#define NCHUNK 9               // ceil(513/64)
#define UNITS  (NCHUNK * FRAMES)      // 2304
#define GRID   (UNITS / 2)            // 1152 snake-paired 2-unit blocks

// ---------------------------------------------------------------------------
// perm = argsort(theta) DESCENDING, stable (O(F^2) rank). Needs 2052 B of ws.
// ---------------------------------------------------------------------------
__global__ __launch_bounds__(1024)
void dstft_perm(const float* __restrict__ raw_win, int* __restrict__ perm)
{
    __shared__ float th[FREQ];
    const int tid = threadIdx.x;
    if (tid < FREQ)
        th[tid] = 10.0f + 1014.0f / (1.0f + expf(-raw_win[tid]));
    __syncthreads();
    if (tid < FREQ) {
        const float ti = th[tid];
        int r = 0;
        for (int j = 0; j < FREQ; ++j) {
            const float tj = th[j];
            r += (tj > ti) || (tj == ti && j < tid);   // descending, stable
        }
        perm[r] = tid;
    }
}

__device__ __forceinline__ float sigmoid_f32(float v)
{
    if (v >= 0.0f) {
        return 1.0f / (1.0f + expf(-v));
    } else {
        const float e = expf(v);
        return e / (1.0f + e);
    }
}

__device__ __forceinline__ float rfl_f32(float v)
{
    return __int_as_float(__builtin_amdgcn_readfirstlane(__float_as_int(v)));
}

struct Unit {
    int   f;        // per-lane frequency index
    float theta;    // per-lane window length
    int   gbase;    // scalar: base + lo (global sample offset)
    float c;        // scalar window center
    int   lo, cnt;  // scalar support range
    int   t;
    bool  active;
};

__device__ __forceinline__ Unit unit_params(int u, int lane, float hop,
        const float* __restrict__ raw_win, const int* __restrict__ perm)
{
    Unit P;
    const int chunk = u >> 8;
    P.t = u & 255;
    const int spos = chunk * 64 + lane;
    P.active = (spos < FREQ);
    int f = 0;
    if (P.active) {
        f = perm ? perm[spos] : spos;
        f = (f < 0) ? 0 : ((f > FREQ - 1) ? (FREQ - 1) : f);  // fault-proof
    }
    P.f = f;
    P.theta = P.active ? (10.0f + sigmoid_f32(raw_win[f]) * 1014.0f) : 10.0f;

    float tmaxv = P.theta;
#pragma unroll
    for (int s = 32; s; s >>= 1)
        tmaxv = fmaxf(tmaxv, __shfl_xor(tmaxv, s, 64));
    const float tmax = rfl_f32(tmaxv);

    // pos/floor: f32-canonical replication of the reference
    float pos = (float)P.t * hop;
    pos = fminf(fmaxf(pos, 0.0f), 65536.0f);
    const float fl = floorf(pos);
    const int base = __builtin_amdgcn_readfirstlane((int)fl);
    P.c = rfl_f32(511.5f + (pos - fl));

    int lo = (int)floorf(P.c - 0.5f * tmax);
    int hi = (int)ceilf (P.c + 0.5f * tmax);
    lo = lo > 0 ? lo : 0;
    hi = hi < (NFFT - 1) ? hi : (NFFT - 1);
    int cnt = hi - lo + 1;
    cnt = cnt < 0 ? 0 : (cnt > NFFT ? NFFT : cnt);
    P.lo    = __builtin_amdgcn_readfirstlane(lo);
    P.cnt   = __builtin_amdgcn_readfirstlane(cnt);
    P.gbase = base + P.lo;
    return P;
}

// compute + cross-wave combine + store for one unit (assumes xlds staged)
__device__ __forceinline__ void process_unit(const Unit& P, int q, int lane,
    const float4* __restrict__ xlds, float (*part)[64][9],
    float* __restrict__ out, int out_size, int stft_mode)
{
    const int s0     = P.lo + (P.cnt * q) / NWAVE;
    const int s1     = P.lo + (P.cnt * (q + 1)) / NWAVE;
    const int segcnt = s1 - s0;

    const float invth = 1.0f / P.theta;
    float r = ((float)s0 - P.c) * invth;        // window arg, revolutions

    // phasor init at n=s0 and step: exact int reduction + hw trig (rev)
    const float sdr = (float)P.f * (1.0f / 1024.0f);
    const float cd  = __builtin_amdgcn_cosf(sdr);
    const float sd  = __builtin_amdgcn_sinf(sdr);
    int m0 = (P.f * s0) & (NFFT - 1);
    m0 = (m0 >= 512) ? (m0 - 1024) : m0;
    const float p0 = (float)m0 * (1.0f / 1024.0f);
    float ca = __builtin_amdgcn_cosf(p0);
    float sa = __builtin_amdgcn_sinf(p0);

    float re0=0.f, re1=0.f, re2=0.f, re3=0.f;
    float sm0=0.f, sm1=0.f, sm2=0.f, sm3=0.f;

    const float4* __restrict__ xp = &xlds[s0 - P.lo];
#pragma unroll 4
    for (int i = 0; i < segcnt; ++i) {
        // med3 clamp; cos(2*pi*(+-0.5)) = -1 -> w = 0 outside support
        const float rc = __builtin_amdgcn_fmed3f(r, -0.5f, 0.5f);
        const float w  = fmaf(0.5f, __builtin_amdgcn_cosf(rc), 0.5f);
        const float wc  = w * ca;
        const float wsn = w * sa;
        const float4 v = xp[i];                 // ds_read_b128 broadcast
        re0 = fmaf(v.x, wc, re0);  sm0 = fmaf(v.x, wsn, sm0);
        re1 = fmaf(v.y, wc, re1);  sm1 = fmaf(v.y, wsn, sm1);
        re2 = fmaf(v.z, wc, re2);  sm2 = fmaf(v.z, wsn, sm2);
        re3 = fmaf(v.w, wc, re3);  sm3 = fmaf(v.w, wsn, sm3);
        const float nca = fmaf(ca, cd, -(sa * sd));
        const float nsa = fmaf(sa, cd,   ca * sd);
        ca = nca; sa = nsa;
        r += invth;
    }

    // cross-wave combine; part aliases xlds -> fence xlds reads first
    __syncthreads();
    part[q][lane][0] = re0;  part[q][lane][1] = re1;
    part[q][lane][2] = re2;  part[q][lane][3] = re3;
    part[q][lane][4] = sm0;  part[q][lane][5] = sm1;
    part[q][lane][6] = sm2;  part[q][lane][7] = sm3;
    __syncthreads();

    // parallel epilogue: thread = (lane, batch=q)
    if (P.active) {
        float res = 0.f, sms = 0.f;
#pragma unroll
        for (int p = 0; p < NWAVE; ++p) {
            res += part[p][lane][q];
            sms += part[p][lane][4 + q];
        }
        const float re = res;
        const float im = -sms;
        const int idx = q * (FREQ * FRAMES) + P.f * FRAMES + P.t;
        if (idx < out_size)
            out[idx] = sqrtf(fmaf(re, re, im * im)) + 1e-12f;   // spec
        if (stft_mode == 2) {
            if (BFT + 2 * idx + 1 < out_size) {
                out[BFT + 2 * idx]     = re;
                out[BFT + 2 * idx + 1] = im;
            }
        } else {
            if (BFT + idx < out_size)
                out[BFT + idx] = re;            // complex stored as f32 real
        }
    }
}

// ---------------------------------------------------------------------------
// Block = 4 waves = 256 thr, TWO snake-paired units {b, 2303-b} (chunk c
// pairs 8-c -> uniform block duration). Unit 2's staging loads are issued in
// the prologue into 12 VGPRs (drain piggybacks on unit 1's staging barrier),
// so phase-2 staging is a latency-free ds_write. LDS 16 KB (part aliased).
// ---------------------------------------------------------------------------
__global__ __launch_bounds__(NTHR)
void dstft_main(const float* __restrict__ x,
                const float* __restrict__ raw_win,
                const float* __restrict__ raw_hop,
                const int* __restrict__ perm,      // may be null (unsorted)
                float* __restrict__ out, int out_size, int stft_mode)
{
    const int tid  = threadIdx.x;
    const int lane = tid & 63;
    const int q    = tid >> 6;               // wave id = n-segment = batch

    __shared__ __align__(16) unsigned char smem[NFFT * sizeof(float4)]; //16KB
    float4* xlds = reinterpret_cast<float4*>(smem);
    float (*part)[64][9] = reinterpret_cast<float (*)[64][9]>(smem);

    const float hop = 1.0f + sigmoid_f32(raw_hop[0]) * 255.0f;
    const int u1 = (int)blockIdx.x;
    const int u2 = UNITS - 1 - u1;           // chunk(u2) in [4,8]

    const Unit P1 = unit_params(u1, lane, hop, raw_win, perm);
    const Unit P2 = unit_params(u2, lane, hop, raw_win, perm);

    // ---- prefetch unit-2 staging into regs (clamped; cnt2 <= ~620) ----
    const int c2m = P2.cnt - 1;
    int j0 = tid;            j0 = j0 < c2m ? j0 : c2m;
    int j1 = tid + NTHR;     j1 = j1 < c2m ? j1 : c2m;
    int j2 = tid + 2*NTHR;   j2 = j2 < c2m ? j2 : c2m;
    float4 pf0, pf1, pf2;
    pf0.x = x[P2.gbase + j0];              pf0.y = x[P2.gbase + j0 + SIGLEN];
    pf0.z = x[P2.gbase + j0 + 2*SIGLEN];   pf0.w = x[P2.gbase + j0 + 3*SIGLEN];
    pf1.x = x[P2.gbase + j1];              pf1.y = x[P2.gbase + j1 + SIGLEN];
    pf1.z = x[P2.gbase + j1 + 2*SIGLEN];   pf1.w = x[P2.gbase + j1 + 3*SIGLEN];
    pf2.x = x[P2.gbase + j2];              pf2.y = x[P2.gbase + j2 + SIGLEN];
    pf2.z = x[P2.gbase + j2 + 2*SIGLEN];   pf2.w = x[P2.gbase + j2 + 3*SIGLEN];

    // ---- stage unit 1 (coalesced float4 rows) ----
    for (int n = tid; n < P1.cnt; n += NTHR) {
        float4 v;
        v.x = x[P1.gbase + n];
        v.y = x[P1.gbase + n + SIGLEN];
        v.z = x[P1.gbase + n + 2 * SIGLEN];
        v.w = x[P1.gbase + n + 3 * SIGLEN];
        xlds[n] = v;
    }
    __syncthreads();                          // drains stage1 + prefetch

    process_unit(P1, q, lane, xlds, part, out, out_size, stft_mode);

    __syncthreads();                          // part reads done -> reuse xlds
    if (tid            < P2.cnt) xlds[tid]            = pf0;
    if (tid +   NTHR   < P2.cnt) xlds[tid +   NTHR]   = pf1;
    if (tid + 2*NTHR   < P2.cnt) xlds[tid + 2*NTHR]   = pf2;
    for (int n = 3*NTHR + tid; n < P2.cnt; n += NTHR) {  // paranoia tail
        float4 v;
        v.x = x[P2.gbase + n];
        v.y = x[P2.gbase + n + SIGLEN];
        v.z = x[P2.gbase + n + 2 * SIGLEN];
        v.w = x[P2.gbase + n + 3 * SIGLEN];
        xlds[n] = v;
    }
    __syncthreads();

    process_unit(P2, q, lane, xlds, part, out, out_size, stft_mode);
}

// ---------------------------------------------------------------------------
extern "C" void kernel_launch(void* const* d_in, const int* in_sizes, int n_in,
                              void* d_out, int out_size, void* d_ws, size_t ws_size,
                              hipStream_t stream)
{
    const float* x       = (const float*)d_in[0];
    const float* raw_win = (const float*)d_in[1];
    const float* raw_hop = (const float*)d_in[2];
    float* out = (float*)d_out;

    int* perm = nullptr;
    if (d_ws != nullptr && ws_size >= 4096) {
        perm = (int*)d_ws;
        dstft_perm<<<1, 1024, 0, stream>>>(raw_win, perm);
    }
    const int stft_mode = (out_size >= 3 * BFT) ? 2 : 1;
    dstft_main<<<GRID, NTHR, 0, stream>>>(
        x, raw_win, raw_hop, perm, out, out_size, stft_mode);
}

// Round 12
// 57.221 us; speedup vs baseline: 1.1120x; 1.1120x over previous
//
#include <hip/hip_runtime.h>
#include <math.h>

#define NFFT   1024
#define FREQ   513
#define FRAMES 256
#define SIGLEN 66560          // 256*256 + 1024
#define NB     4
#define BFT    (NB * FREQ * FRAMES)   // 525312
#define NWAVE  4               // waves per block (n-loop split factor)
#define NTHR   (64 * NWAVE)    // 256
#define NCHUNK 9               // ceil(513/64)
#define UNITS  (NCHUNK * FRAMES)      // 2304 blocks, 1 unit each (LPT order)

typedef float f32x2 __attribute__((ext_vector_type(2)));

// ---------------------------------------------------------------------------
// perm = argsort(theta) DESCENDING, stable (O(F^2) rank). Needs 2052 B of ws.
// ---------------------------------------------------------------------------
__global__ __launch_bounds__(1024)
void dstft_perm(const float* __restrict__ raw_win, int* __restrict__ perm)
{
    __shared__ float th[FREQ];
    const int tid = threadIdx.x;
    if (tid < FREQ)
        th[tid] = 10.0f + 1014.0f / (1.0f + expf(-raw_win[tid]));
    __syncthreads();
    if (tid < FREQ) {
        const float ti = th[tid];
        int r = 0;
        for (int j = 0; j < FREQ; ++j) {
            const float tj = th[j];
            r += (tj > ti) || (tj == ti && j < tid);   // descending, stable
        }
        perm[r] = tid;
    }
}

__device__ __forceinline__ float sigmoid_f32(float v)
{
    if (v >= 0.0f) {
        return 1.0f / (1.0f + expf(-v));
    } else {
        const float e = expf(v);
        return e / (1.0f + e);
    }
}

__device__ __forceinline__ float rfl_f32(float v)
{
    return __int_as_float(__builtin_amdgcn_readfirstlane(__float_as_int(v)));
}

// ---------------------------------------------------------------------------
// Block = 4 waves = 256 thr, ONE unit (t, 64-f chunk) per block, 2304 blocks
// in descending-theta (LPT) order. x staged into LDS float4 rows over [lo,hi];
// part[] aliases xlds (sync-separated) => 16.4 KB LDS. Inner loop in PACKED
// f32 (v_pk_fma_f32 via llvm.fma.v2f32): acc[b] = {re,im}, phasor packed.
// ---------------------------------------------------------------------------
__global__ __launch_bounds__(NTHR)
void dstft_main(const float* __restrict__ x,
                const float* __restrict__ raw_win,
                const float* __restrict__ raw_hop,
                const int* __restrict__ perm,      // may be null (unsorted)
                float* __restrict__ out, int out_size, int stft_mode)
{
    const int tid  = threadIdx.x;
    const int lane = tid & 63;
    const int q    = tid >> 6;               // wave id = n-segment = batch

    __shared__ __align__(16) unsigned char smem[NFFT * sizeof(float4)]; //16KB
    float4* xlds = reinterpret_cast<float4*>(smem);
    float (*part)[64][9] = reinterpret_cast<float (*)[64][9]>(smem);

    const int u     = (int)blockIdx.x;
    const int chunk = u >> 8;                // 0..8 (desc-theta order)
    const int t     = u & 255;
    const int spos  = chunk * 64 + lane;
    const bool active = (spos < FREQ);

    int f = 0;
    if (active) {
        f = perm ? perm[spos] : spos;
        f = (f < 0) ? 0 : ((f > FREQ - 1) ? (FREQ - 1) : f);
    }
    const float theta = active
        ? (10.0f + sigmoid_f32(raw_win[f]) * 1014.0f)
        : 10.0f;

    // wave-wide max theta -> SGPR
    float tmaxv = theta;
#pragma unroll
    for (int s = 32; s; s >>= 1)
        tmaxv = fmaxf(tmaxv, __shfl_xor(tmaxv, s, 64));
    const float tmax = rfl_f32(tmaxv);

    // pos/floor: f32-canonical replication of the reference (uniform)
    const float hop = 1.0f + sigmoid_f32(raw_hop[0]) * 255.0f;
    float pos = (float)t * hop;
    pos = fminf(fmaxf(pos, 0.0f), 65536.0f);
    const float fl   = floorf(pos);
    const int   base = __builtin_amdgcn_readfirstlane((int)fl);
    const float c    = rfl_f32(511.5f + (pos - fl));

    int lo = (int)floorf(c - 0.5f * tmax);
    int hi = (int)ceilf (c + 0.5f * tmax);
    lo = lo > 0 ? lo : 0;
    hi = hi < (NFFT - 1) ? hi : (NFFT - 1);
    int cnt = hi - lo + 1;
    cnt = cnt < 0 ? 0 : (cnt > NFFT ? NFFT : cnt);
    lo  = __builtin_amdgcn_readfirstlane(lo);
    cnt = __builtin_amdgcn_readfirstlane(cnt);

    // ---- stage x tile [lo, lo+cnt) into LDS (coalesced) ----
    for (int n = lo + tid; n < lo + cnt; n += NTHR) {
        float4 v;
        v.x = x[base + n];
        v.y = x[base + n + SIGLEN];
        v.z = x[base + n + 2 * SIGLEN];
        v.w = x[base + n + 3 * SIGLEN];
        xlds[n - lo] = v;
    }
    __syncthreads();

    const int s0     = lo + (cnt * q) / NWAVE;
    const int s1     = lo + (cnt * (q + 1)) / NWAVE;
    const int segcnt = s1 - s0;

    const float invth = 1.0f / theta;
    float r = ((float)s0 - c) * invth;       // window arg, revolutions

    // phasor init at n=s0 and step: exact int reduction + hw trig (rev)
    const float sdr = (float)f * (1.0f / 1024.0f);
    const float cd  = __builtin_amdgcn_cosf(sdr);
    const float sd  = __builtin_amdgcn_sinf(sdr);
    int m0 = (f * s0) & (NFFT - 1);
    m0 = (m0 >= 512) ? (m0 - 1024) : m0;
    const float p0 = (float)m0 * (1.0f / 1024.0f);

    f32x2 p;                                  // {ca, sa}
    p.x = __builtin_amdgcn_cosf(p0);
    p.y = __builtin_amdgcn_sinf(p0);
    const f32x2 cdv = { cd,  cd };
    const f32x2 sdv = { -sd, sd };

    f32x2 acc0 = {0.f, 0.f}, acc1 = {0.f, 0.f};
    f32x2 acc2 = {0.f, 0.f}, acc3 = {0.f, 0.f};   // {re_b, sum_b}

    const float4* __restrict__ xp = &xlds[s0 - lo];
#pragma unroll 4
    for (int i = 0; i < segcnt; ++i) {
        // med3 clamp; cos(2*pi*(+-0.5)) = -1 -> w = 0 outside support
        const float rc = __builtin_amdgcn_fmed3f(r, -0.5f, 0.5f);
        const float w  = fmaf(0.5f, __builtin_amdgcn_cosf(rc), 0.5f);
        const f32x2 w2  = { w, w };
        const f32x2 wcs = w2 * p;             // v_pk_mul: {w*ca, w*sa}
        const float4 v = xp[i];               // ds_read_b128 broadcast
        const f32x2 v0 = { v.x, v.x }, v1 = { v.y, v.y };
        const f32x2 v2 = { v.z, v.z }, v3 = { v.w, v.w };
        acc0 = __builtin_elementwise_fma(v0, wcs, acc0);   // v_pk_fma_f32
        acc1 = __builtin_elementwise_fma(v1, wcs, acc1);
        acc2 = __builtin_elementwise_fma(v2, wcs, acc2);
        acc3 = __builtin_elementwise_fma(v3, wcs, acc3);
        const f32x2 ps = p.yx;                // {sa, ca} (op_sel-foldable)
        p = __builtin_elementwise_fma(p, cdv, ps * sdv);   // rotate
        r += invth;
    }

    // ---- cross-wave combine; part aliases xlds, fence reads first ----
    __syncthreads();
    part[q][lane][0] = acc0.x;  part[q][lane][1] = acc1.x;
    part[q][lane][2] = acc2.x;  part[q][lane][3] = acc3.x;
    part[q][lane][4] = acc0.y;  part[q][lane][5] = acc1.y;
    part[q][lane][6] = acc2.y;  part[q][lane][7] = acc3.y;
    __syncthreads();

    // ---- epilogue: 4 waves in parallel, thread = (lane, batch=q) ----
    if (active) {
        float res = 0.f, sms = 0.f;
#pragma unroll
        for (int pw = 0; pw < NWAVE; ++pw) {
            res += part[pw][lane][q];
            sms += part[pw][lane][4 + q];
        }
        const float re = res;
        const float im = -sms;
        const int idx = q * (FREQ * FRAMES) + f * FRAMES + t;
        if (idx < out_size)
            out[idx] = sqrtf(fmaf(re, re, im * im)) + 1e-12f;   // spec
        if (stft_mode == 2) {
            if (BFT + 2 * idx + 1 < out_size) {
                out[BFT + 2 * idx]     = re;
                out[BFT + 2 * idx + 1] = im;
            }
        } else {
            if (BFT + idx < out_size)
                out[BFT + idx] = re;         // complex stored as f32 real
        }
    }
}

// ---------------------------------------------------------------------------
extern "C" void kernel_launch(void* const* d_in, const int* in_sizes, int n_in,
                              void* d_out, int out_size, void* d_ws, size_t ws_size,
                              hipStream_t stream)
{
    const float* x       = (const float*)d_in[0];
    const float* raw_win = (const float*)d_in[1];
    const float* raw_hop = (const float*)d_in[2];
    float* out = (float*)d_out;

    int* perm = nullptr;
    if (d_ws != nullptr && ws_size >= 4096) {
        perm = (int*)d_ws;
        dstft_perm<<<1, 1024, 0, stream>>>(raw_win, perm);
    }
    const int stft_mode = (out_size >= 3 * BFT) ? 2 : 1;
    dstft_main<<<UNITS, NTHR, 0, stream>>>(
        x, raw_win, raw_hop, perm, out, out_size, stft_mode);
}

// Round 13
// 56.911 us; speedup vs baseline: 1.1180x; 1.0054x over previous
//
#include <hip/hip_runtime.h>
#include <math.h>

#define NFFT   1024
#define FREQ   513
#define FRAMES 256
#define SIGLEN 66560          // 256*256 + 1024
#define NB     4
#define BFT    (NB * FREQ * FRAMES)   // 525312
#define NWAVE  4               // waves per block (n-loop split factor)
#define NTHR   (64 * NWAVE)    // 256
#define NCHUNK 9               // ceil(513/64)
#define UNITS  (NCHUNK * FRAMES)      // 2304 blocks, 1 unit each (LPT order)

typedef float f32x2 __attribute__((ext_vector_type(2)));

__device__ __forceinline__ float sigmoid_f32(float v)
{
    if (v >= 0.0f) {
        return 1.0f / (1.0f + expf(-v));
    } else {
        const float e = expf(v);
        return e / (1.0f + e);
    }
}

__device__ __forceinline__ float rfl_f32(float v)
{
    return __int_as_float(__builtin_amdgcn_readfirstlane(__float_as_int(v)));
}

// ---------------------------------------------------------------------------
// Setup: sorted-f (desc theta, stable), per-chunk theta-max, per-frame
// {base, center} tables. ws layout (bytes): sf u16[513]@0, ctmax f32[9]@1028,
// tbase i32[256]@1064, tc f32[256]@2088 -> 3112 B total.
// ---------------------------------------------------------------------------
__global__ __launch_bounds__(1024)
void dstft_setup(const float* __restrict__ raw_win,
                 const float* __restrict__ raw_hop,
                 unsigned short* __restrict__ sf,
                 float* __restrict__ ctmax,
                 int* __restrict__ tbase,
                 float* __restrict__ tc)
{
    __shared__ float th[FREQ];
    const int tid = threadIdx.x;
    if (tid < FREQ)
        th[tid] = 10.0f + sigmoid_f32(raw_win[tid]) * 1014.0f;
    __syncthreads();
    if (tid < FREQ) {
        const float ti = th[tid];
        int r = 0;
        for (int j = 0; j < FREQ; ++j) {
            const float tj = th[j];
            r += (tj > ti) || (tj == ti && j < tid);   // descending, stable
        }
        sf[r] = (unsigned short)tid;
        if ((r & 63) == 0) ctmax[r >> 6] = ti;         // chunk max (desc)
    }
    if (tid < FRAMES) {
        // f32-canonical replication of the reference pos computation
        const float hop = 1.0f + sigmoid_f32(raw_hop[0]) * 255.0f;
        float pos = (float)tid * hop;
        pos = fminf(fmaxf(pos, 0.0f), 65536.0f);
        const float fl = floorf(pos);
        tbase[tid] = (int)fl;
        tc[tid]    = 511.5f + (pos - fl);
    }
}

// ---------------------------------------------------------------------------
// Block = 4 waves = 256 thr, ONE unit (t, 64-f chunk) per block, 2304 blocks
// LPT order. x staged into LDS float4 rows over [lo,hi]; part[] aliases xlds.
// Inner loop: batch-packed f32x2 (v01/v23 are free halves of ds_read_b128).
// Prologue params from d_ws tables (no shfl chain, no per-block hop/pos).
// ---------------------------------------------------------------------------
__global__ __launch_bounds__(NTHR, 8)
void dstft_main(const float* __restrict__ x,
                const float* __restrict__ raw_win,
                const float* __restrict__ raw_hop,
                const unsigned short* __restrict__ sf,   // may be null
                const float* __restrict__ ctmax,
                const int* __restrict__ tbase,
                const float* __restrict__ tc,
                float* __restrict__ out, int out_size, int stft_mode)
{
    const int tid  = threadIdx.x;
    const int lane = tid & 63;
    const int q    = tid >> 6;               // wave id = n-segment = batch

    __shared__ __align__(16) unsigned char smem[NFFT * sizeof(float4)]; //16KB
    float4* xlds = reinterpret_cast<float4*>(smem);
    float (*part)[64][9] = reinterpret_cast<float (*)[64][9]>(smem);

    const int u     = (int)blockIdx.x;
    const int chunk = u >> 8;                // 0..8 (desc-theta order)
    const int t     = u & 255;
    const int spos  = chunk * 64 + lane;
    const bool active = (spos < FREQ);

    int   f = 0;
    float theta, tmax, c;
    int   base;

    if (sf) {
        if (active) {
            f = (int)sf[spos];
            f = (f < 0) ? 0 : ((f > FREQ - 1) ? (FREQ - 1) : f);
        }
        theta = active ? (10.0f + sigmoid_f32(raw_win[f]) * 1014.0f) : 10.0f;
        tmax  = rfl_f32(ctmax[chunk]);
        base  = __builtin_amdgcn_readfirstlane(tbase[t]);
        c     = rfl_f32(tc[t]);
    } else {
        // fallback (no ws): natural f order, inline params
        if (active) f = spos;
        theta = active ? (10.0f + sigmoid_f32(raw_win[f]) * 1014.0f) : 10.0f;
        float tmaxv = theta;
#pragma unroll
        for (int s = 32; s; s >>= 1)
            tmaxv = fmaxf(tmaxv, __shfl_xor(tmaxv, s, 64));
        tmax = rfl_f32(tmaxv);
        const float hop = 1.0f + sigmoid_f32(raw_hop[0]) * 255.0f;
        float pos = (float)t * hop;
        pos = fminf(fmaxf(pos, 0.0f), 65536.0f);
        const float fl = floorf(pos);
        base = __builtin_amdgcn_readfirstlane((int)fl);
        c    = rfl_f32(511.5f + (pos - fl));
    }

    int lo = (int)floorf(c - 0.5f * tmax);
    int hi = (int)ceilf (c + 0.5f * tmax);
    lo = lo > 0 ? lo : 0;
    hi = hi < (NFFT - 1) ? hi : (NFFT - 1);
    int cnt = hi - lo + 1;
    cnt = cnt < 0 ? 0 : (cnt > NFFT ? NFFT : cnt);
    lo  = __builtin_amdgcn_readfirstlane(lo);
    cnt = __builtin_amdgcn_readfirstlane(cnt);

    // ---- stage x tile [lo, lo+cnt) into LDS (coalesced) ----
    for (int n = lo + tid; n < lo + cnt; n += NTHR) {
        float4 v;
        v.x = x[base + n];
        v.y = x[base + n + SIGLEN];
        v.z = x[base + n + 2 * SIGLEN];
        v.w = x[base + n + 3 * SIGLEN];
        xlds[n - lo] = v;
    }
    __syncthreads();

    const int s0     = lo + (cnt * q) / NWAVE;
    const int s1     = lo + (cnt * (q + 1)) / NWAVE;
    const int segcnt = s1 - s0;

    const float invth = 1.0f / theta;
    float r = ((float)s0 - c) * invth;       // window arg, revolutions

    // phasor init at n=s0 and step: exact int reduction + hw trig (rev)
    const float sdr = (float)f * (1.0f / 1024.0f);
    const float cd  = __builtin_amdgcn_cosf(sdr);
    const float sd  = __builtin_amdgcn_sinf(sdr);
    int m0 = (f * s0) & (NFFT - 1);
    m0 = (m0 >= 512) ? (m0 - 1024) : m0;
    const float p0 = (float)m0 * (1.0f / 1024.0f);

    f32x2 p;                                  // {ca, sa}
    p.x = __builtin_amdgcn_cosf(p0);
    p.y = __builtin_amdgcn_sinf(p0);
    const f32x2 cdv = { cd,  cd };
    const f32x2 sdv = { -sd, sd };

    // batch-packed accumulators: {b0,b1} and {b2,b3} for re and im-sum
    f32x2 are01 = {0.f, 0.f}, are23 = {0.f, 0.f};
    f32x2 aim01 = {0.f, 0.f}, aim23 = {0.f, 0.f};

    const float4* __restrict__ xp = &xlds[s0 - lo];
#pragma unroll 4
    for (int i = 0; i < segcnt; ++i) {
        // med3 clamp; cos(2*pi*(+-0.5)) = -1 -> w = 0 outside support
        const float rc = __builtin_amdgcn_fmed3f(r, -0.5f, 0.5f);
        const float w  = fmaf(0.5f, __builtin_amdgcn_cosf(rc), 0.5f);
        const float wc  = w * p.x;
        const float wsn = w * p.y;
        const f32x2 wcv = { wc,  wc  };       // 1 splat mov
        const f32x2 wsv = { wsn, wsn };       // 1 splat mov
        const float4 v = xp[i];               // ds_read_b128 broadcast
        const f32x2 v01 = { v.x, v.y };       // free: aligned halves of load
        const f32x2 v23 = { v.z, v.w };
        are01 = __builtin_elementwise_fma(v01, wcv, are01);   // v_pk_fma_f32
        are23 = __builtin_elementwise_fma(v23, wcv, are23);
        aim01 = __builtin_elementwise_fma(v01, wsv, aim01);
        aim23 = __builtin_elementwise_fma(v23, wsv, aim23);
        const f32x2 ps = p.yx;
        p = __builtin_elementwise_fma(p, cdv, ps * sdv);      // rotate
        r += invth;
    }

    // ---- cross-wave combine; part aliases xlds, fence reads first ----
    __syncthreads();
    part[q][lane][0] = are01.x;  part[q][lane][1] = are01.y;
    part[q][lane][2] = are23.x;  part[q][lane][3] = are23.y;
    part[q][lane][4] = aim01.x;  part[q][lane][5] = aim01.y;
    part[q][lane][6] = aim23.x;  part[q][lane][7] = aim23.y;
    __syncthreads();

    // ---- epilogue: 4 waves in parallel, thread = (lane, batch=q) ----
    if (active) {
        float res = 0.f, sms = 0.f;
#pragma unroll
        for (int pw = 0; pw < NWAVE; ++pw) {
            res += part[pw][lane][q];
            sms += part[pw][lane][4 + q];
        }
        const float re = res;
        const float im = -sms;
        const int idx = q * (FREQ * FRAMES) + f * FRAMES + t;
        if (idx < out_size)
            out[idx] = sqrtf(fmaf(re, re, im * im)) + 1e-12f;   // spec
        if (stft_mode == 2) {
            if (BFT + 2 * idx + 1 < out_size) {
                out[BFT + 2 * idx]     = re;
                out[BFT + 2 * idx + 1] = im;
            }
        } else {
            if (BFT + idx < out_size)
                out[BFT + idx] = re;         // complex stored as f32 real
        }
    }
}

// ---------------------------------------------------------------------------
extern "C" void kernel_launch(void* const* d_in, const int* in_sizes, int n_in,
                              void* d_out, int out_size, void* d_ws, size_t ws_size,
                              hipStream_t stream)
{
    const float* x       = (const float*)d_in[0];
    const float* raw_win = (const float*)d_in[1];
    const float* raw_hop = (const float*)d_in[2];
    float* out = (float*)d_out;

    unsigned short* sf    = nullptr;
    float*          ctmax = nullptr;
    int*            tbase = nullptr;
    float*          tc    = nullptr;
    if (d_ws != nullptr && ws_size >= 3200) {
        sf    = (unsigned short*)d_ws;                   // 1028 B
        ctmax = (float*)((char*)d_ws + 1028);            // 36 B
        tbase = (int*)  ((char*)d_ws + 1064);            // 1024 B
        tc    = (float*)((char*)d_ws + 2088);            // 1024 B (end 3112)
        dstft_setup<<<1, 1024, 0, stream>>>(raw_win, raw_hop,
                                            sf, ctmax, tbase, tc);
    }
    const int stft_mode = (out_size >= 3 * BFT) ? 2 : 1;
    dstft_main<<<UNITS, NTHR, 0, stream>>>(
        x, raw_win, raw_hop, sf, ctmax, tbase, tc, out, out_size, stft_mode);
}